// Round 11
// baseline (125.689 us; speedup 1.0000x reference)
//
#include <hip/hip_runtime.h>

// AdditiveAttention: b=4, n_q=64, s=1024, Q_DIM=K_DIM=HID=VDIM=512, f32 in/out.
// R11: 4 nodes = convert, proj(MFMA, writes Eq/Ek=exp2), scores_av (FUSED:
// full-h scores w/ d=fma(Eq,Ek,1) + paired rcp -> e=exp2 -> in-block AV
// partial + shuffle row-sums, 512 blocks), reduce (sum 32 s-chunks + norm).

static constexpr int SLEN = 1024;
static constexpr int DIM  = 512;
static constexpr float TANH_SCALE = 2.885390081777927f;  // 2*log2(e)

typedef __attribute__((ext_vector_type(8))) short bf16x8;
typedef __attribute__((ext_vector_type(4))) float f32x4;

__device__ __forceinline__ float fast_exp2(float x) { return __builtin_amdgcn_exp2f(x); }
__device__ __forceinline__ float fast_rcp(float x)  { return __builtin_amdgcn_rcpf(x); }

__device__ __forceinline__ unsigned int f2bf(float f) {
    unsigned int u = __float_as_uint(f);
    u += 0x7FFF + ((u >> 16) & 1);   // RNE
    return u >> 16;
}

__device__ __forceinline__ void async_copy16(const void* g, void* l) {
    __builtin_amdgcn_global_load_lds(
        (const __attribute__((address_space(1))) unsigned int*)g,
        (__attribute__((address_space(3))) unsigned int*)l, 16, 0, 0);
}

// f32 -> bf16 pre-convert: queries (131072), keys (2097152), W1 (524288) elems.
__global__ __launch_bounds__(256) void convert_bf16(
    const float* __restrict__ q, const float* __restrict__ k,
    const float* __restrict__ w, unsigned short* __restrict__ qb,
    unsigned short* __restrict__ kb, unsigned short* __restrict__ wb)
{
    int id = blockIdx.x * 256 + threadIdx.x;
    const float* src; unsigned short* dst; int off;
    if (id < 32768)        { src = q; dst = qb; off = id; }
    else if (id < 557056)  { src = k; dst = kb; off = id - 32768; }
    else                   { src = w; dst = wb; off = id - 557056; }
    float4 v = ((const float4*)src)[off];
    ushort4 o;
    o.x = (unsigned short)f2bf(v.x); o.y = (unsigned short)f2bf(v.y);
    o.z = (unsigned short)f2bf(v.z); o.w = (unsigned short)f2bf(v.w);
    ((ushort4*)dst)[off] = o;
}

// Fused q_proj/k_proj GEMM, bf16 MFMA, global_load_lds staging.
// E[m][n] = exp2( (sum_k A[m][k]*W1[n][col_off+k] + bias[n]) * TANH_SCALE )
// blocks 0..511: k_proj -> Ek; 512..543: q_proj -> Eq. Tile 64x64, BK=64.
__global__ __launch_bounds__(256) void proj_mfma(
    const unsigned short* __restrict__ qb, const unsigned short* __restrict__ kb,
    const unsigned short* __restrict__ wb, const float* __restrict__ b1,
    float* __restrict__ qp, float* __restrict__ kp)
{
    __shared__ __align__(16) unsigned short As[64][64];
    __shared__ __align__(16) unsigned short Ws[64][64];

    const int bx = blockIdx.x;
    const unsigned short* A; float* C; const float* bias; int mb, nb, col_off;
    if (bx < 512) {
        A = kb; C = kp; bias = b1; col_off = 512;
        mb = (bx >> 3) * 64; nb = (bx & 7) * 64;
    } else {
        int b2 = bx - 512;
        A = qb; C = qp; bias = nullptr; col_off = 0;
        mb = (b2 >> 3) * 64; nb = (b2 & 7) * 64;
    }

    const int t = threadIdx.x;
    const int l = t & 63;
    const int wv = t >> 6;
    const int wm = (wv & 1) * 32;
    const int wn = (wv >> 1) * 32;
    const int lane16 = l & 15;
    const int quad   = l >> 4;
    const int r8   = l >> 3;
    const int schk = (l & 7) ^ r8;

    f32x4 acc[2][2] = {{{0.f,0.f,0.f,0.f},{0.f,0.f,0.f,0.f}},
                       {{0.f,0.f,0.f,0.f},{0.f,0.f,0.f,0.f}}};

    for (int kc = 0; kc < DIM; kc += 64) {
#pragma unroll
        for (int i = 0; i < 2; ++i) {
            int rbase = wv * 16 + i * 8;
            async_copy16(A + (size_t)(mb + rbase + r8) * DIM + kc + schk * 8, &As[rbase][0]);
            async_copy16(wb + (size_t)(nb + rbase + r8) * 1024 + col_off + kc + schk * 8, &Ws[rbase][0]);
        }
        __syncthreads();

#pragma unroll
        for (int ks = 0; ks < 2; ++ks) {
            int cc = ks * 4 + quad;
            int sw = (cc ^ (lane16 & 7)) << 3;
            bf16x8 a0  = *(const bf16x8*)&As[wm + lane16][sw];
            bf16x8 a1  = *(const bf16x8*)&As[wm + 16 + lane16][sw];
            bf16x8 b0  = *(const bf16x8*)&Ws[wn + lane16][sw];
            bf16x8 b1v = *(const bf16x8*)&Ws[wn + 16 + lane16][sw];
            acc[0][0] = __builtin_amdgcn_mfma_f32_16x16x32_bf16(a0, b0,  acc[0][0], 0, 0, 0);
            acc[0][1] = __builtin_amdgcn_mfma_f32_16x16x32_bf16(a0, b1v, acc[0][1], 0, 0, 0);
            acc[1][0] = __builtin_amdgcn_mfma_f32_16x16x32_bf16(a1, b0,  acc[1][0], 0, 0, 0);
            acc[1][1] = __builtin_amdgcn_mfma_f32_16x16x32_bf16(a1, b1v, acc[1][1], 0, 0, 0);
        }
        __syncthreads();
    }

#pragma unroll
    for (int mi = 0; mi < 2; ++mi) {
#pragma unroll
        for (int ni = 0; ni < 2; ++ni) {
            int col = nb + wn + 16 * ni + lane16;
            float bv = bias ? bias[col] : 0.0f;
#pragma unroll
            for (int r = 0; r < 4; ++r) {
                int row = mb + wm + 16 * mi + quad * 4 + r;
                C[(size_t)row * DIM + col] = fast_exp2((acc[mi][ni][r] + bv) * TANH_SCALE);
            }
        }
    }
}

// FUSED scores+e+AV-partial+rowsums. Tile 16q x 32s, FULL 512-h sum.
// t[q,s] = sum_h w2[h]/(1+Eq[q][h]*Ek[s][h]); e = exp2(-TANH_SCALE*t);
// pt[st][row][v] = sum_{s in chunk} e*V[s][v]; sums_p[st][row] = sum e.
// Grid (32 st, 4 qt, 4 b) = 512 blocks.
__global__ __launch_bounds__(256) void scores_av(
    const float* __restrict__ qp, const float* __restrict__ kp,
    const float* __restrict__ w2, const float* __restrict__ values,
    float* __restrict__ pt, float* __restrict__ sums_p)
{
    __shared__ __align__(16) float qs[16][68];
    __shared__ __align__(16) float ks[32][68];
    __shared__ __align__(16) float ws2[512];
    __shared__ __align__(16) float es[16][33];
    __shared__ __align__(16) float vs[32][68];

    const int t     = threadIdx.x;
    const int st    = blockIdx.x;
    const int sb    = st * 32;
    const int qt    = blockIdx.y;
    const int bb    = blockIdx.z;
    const int qrow0 = bb * 64 + qt * 16;
    const int krow0 = bb * 1024 + sb;

    if (t < 128) *(float4*)&ws2[t << 2] = *(const float4*)(w2 + (t << 2));

    const int tq = t >> 4;
    const int ts = t & 15;
    float a00 = 0.f, a01 = 0.f, a10 = 0.f, a11 = 0.f;

    for (int kc = 0; kc < DIM; kc += 64) {
        {
            int r = t >> 4, g = (t & 15) << 2;
            *(float4*)&qs[r][g] = *(const float4*)(qp + (size_t)(qrow0 + r) * DIM + kc + g);
        }
#pragma unroll
        for (int rr = 0; rr < 2; ++rr) {
            int idx = t + rr * 256;
            int r = idx >> 4, g = (idx & 15) << 2;
            *(float4*)&ks[r][g] = *(const float4*)(kp + (size_t)(krow0 + r) * DIM + kc + g);
        }
        __syncthreads();
#pragma unroll
        for (int k4 = 0; k4 < 16; ++k4) {
            float4 qv = *(const float4*)&qs[tq][k4 << 2];
            float4 k0 = *(const float4*)&ks[ts][k4 << 2];
            float4 k1 = *(const float4*)&ks[ts + 16][k4 << 2];
            float4 wv = *(const float4*)&ws2[kc + (k4 << 2)];
            {
                float d0 = fmaf(qv.x, k0.x, 1.0f);
                float d1 = fmaf(qv.y, k0.y, 1.0f);
                a00 = fmaf(fmaf(wv.x, d1, wv.y * d0), fast_rcp(d0 * d1), a00);
                float d2 = fmaf(qv.z, k0.z, 1.0f);
                float d3 = fmaf(qv.w, k0.w, 1.0f);
                a01 = fmaf(fmaf(wv.z, d3, wv.w * d2), fast_rcp(d2 * d3), a01);
            }
            {
                float d0 = fmaf(qv.x, k1.x, 1.0f);
                float d1 = fmaf(qv.y, k1.y, 1.0f);
                a10 = fmaf(fmaf(wv.x, d1, wv.y * d0), fast_rcp(d0 * d1), a10);
                float d2 = fmaf(qv.z, k1.z, 1.0f);
                float d3 = fmaf(qv.w, k1.w, 1.0f);
                a11 = fmaf(fmaf(wv.z, d3, wv.w * d2), fast_rcp(d2 * d3), a11);
            }
        }
        __syncthreads();
    }

    // e + per-row partial sums (shuffle over the 16 ts lanes, same tq).
    {
        float e0 = fast_exp2(-TANH_SCALE * (a00 + a01));
        float e1 = fast_exp2(-TANH_SCALE * (a10 + a11));
        es[tq][ts]      = e0;
        es[tq][ts + 16] = e1;
        float v = e0 + e1;
        v += __shfl_xor(v, 1, 64);
        v += __shfl_xor(v, 2, 64);
        v += __shfl_xor(v, 4, 64);
        v += __shfl_xor(v, 8, 64);
        if (ts == 0) sums_p[st * 256 + qrow0 + tq] = v;
    }
    __syncthreads();

    // AV partial: pt[st][qrow0+q8][v] = sum_{s=0..31} es[q8][s] * V[krow0+s][v]
    {
        const int q8 = t >> 4;          // 0..15
        const int v4 = (t & 15) << 2;   // 0..60 within 64-col chunk
#pragma unroll
        for (int vc = 0; vc < 8; ++vc) {
#pragma unroll
            for (int rr = 0; rr < 2; ++rr) {
                int idx = t + rr * 256;
                int r = idx >> 4, g = (idx & 15) << 2;
                *(float4*)&vs[r][g] =
                    *(const float4*)(values + (size_t)(krow0 + r) * DIM + vc * 64 + g);
            }
            __syncthreads();
            float4 acc = {0.f, 0.f, 0.f, 0.f};
#pragma unroll
            for (int s = 0; s < 32; ++s) {
                float ev = es[q8][s];
                float4 vv = *(const float4*)&vs[s][v4];
                acc.x = fmaf(ev, vv.x, acc.x);
                acc.y = fmaf(ev, vv.y, acc.y);
                acc.z = fmaf(ev, vv.z, acc.z);
                acc.w = fmaf(ev, vv.w, acc.w);
            }
            *(float4*)(pt + ((size_t)st * 256 + qrow0 + q8) * DIM + vc * 64 + v4) = acc;
            __syncthreads();
        }
    }
}

// out = (sum_{st=0..31} pt[st]) / (sum_{st} sums_p[st][row]). 32768 float4s.
__global__ __launch_bounds__(256) void reduce_kernel(
    const float* __restrict__ pt, const float* __restrict__ sums_p,
    float* __restrict__ out)
{
    int idx = blockIdx.x * 256 + threadIdx.x;
    const float4* p = (const float4*)pt;
    float4 a = p[idx];
#pragma unroll
    for (int k = 1; k < 32; ++k) {
        float4 v = p[(size_t)k * 32768 + idx];
        a.x += v.x; a.y += v.y; a.z += v.z; a.w += v.w;
    }
    int row = idx >> 7;
    float s = 0.f;
#pragma unroll
    for (int k = 0; k < 32; ++k) s += sums_p[k * 256 + row];
    float r = fast_rcp(s);
    a.x *= r; a.y *= r; a.z *= r; a.w *= r;
    ((float4*)out)[idx] = a;
}

extern "C" void kernel_launch(void* const* d_in, const int* in_sizes, int n_in,
                              void* d_out, int out_size, void* d_ws, size_t ws_size,
                              hipStream_t stream) {
    const float* queries = (const float*)d_in[0];
    const float* keys    = (const float*)d_in[1];
    const float* values  = (const float*)d_in[2];
    const float* W1      = (const float*)d_in[3];
    const float* b1      = (const float*)d_in[4];
    const float* w2      = (const float*)d_in[5];
    float* out = (float*)d_out;

    float* qp     = (float*)d_ws;                   // 131072 f32 (Eq)
    float* kp     = qp + 131072;                    // 2097152 f32 (Ek)
    float* pt     = kp + 2097152;                   // 32 x 131072 f32 (16 MB)
    float* sums_p = pt + 32 * 131072;               // 8192 f32
    unsigned short* qbf = (unsigned short*)(sums_p + 8192);
    unsigned short* kbf = qbf + 131072;
    unsigned short* wbf = kbf + 2097152;
    (void)in_sizes; (void)n_in; (void)ws_size; (void)out_size;

    convert_bf16<<<dim3(2688), 256, 0, stream>>>(queries, keys, W1, qbf, kbf, wbf);
    proj_mfma<<<dim3(544), 256, 0, stream>>>(qbf, kbf, wbf, b1, qp, kp);
    scores_av<<<dim3(32, 4, 4), 256, 0, stream>>>(qp, kp, w2, values, pt, sums_p);
    reduce_kernel<<<dim3(128), 256, 0, stream>>>(pt, sums_p, out);
}